// Round 5
// baseline (411.665 us; speedup 1.0000x reference)
//
#include <hip/hip_runtime.h>
#include <hip/hip_bf16.h>

// Decomposition (all-bf16 operands, GEMMs in the m97 global_load_lds regime):
//   xb   (512x4096  bf16, ws+0)    = cvt(x)
//   Pib  (8192x4096 bf16, ws+92MB) = cvt([Pi; Pi2])
//   Wcat (4096x8192 bf16, ws+28MB) = dequant([W1 | W2])
//   Y32  (512x8192  f32,  ws+4MB) += xb @ Pib^T     (z=4 K-chunks, atomic f32)
//   Ybf  (512x8192  bf16, ws+20MB) = cvt(Y32)
//   out  (512x4096  f32)          += Ybf @ Wcat^T   (z=8 K-chunks, atomic f32)
// GEMM tile: 128x128, BK=32, 4 waves (2x2), wave-tile 64x64, acc 4x4 frags,
// double-buffered LDS (32KB), BOTH operands via global_load_lds(16B).
// Tier dispatch on ws_size: full(156MB) -> mid(92MB) -> low(28MB) -> tiny(12MB).

typedef __bf16 bf16x8 __attribute__((ext_vector_type(8)));
typedef float  f32x4  __attribute__((ext_vector_type(4)));

#define T_DIM   512
#define N_DIM   4096
#define M_DIM   4096
#define K2_DIM  8192
#define INV_SQRT_G 0.08838834764831843f   // 1/sqrt(128)

typedef const __attribute__((address_space(1))) unsigned int as1_u32;
typedef __attribute__((address_space(3)))       unsigned int as3_u32;

__device__ __forceinline__ void gload16(const void* g, void* l) {
    // per-lane global src; LDS dst = wave-uniform base + lane*16 (m104)
    __builtin_amdgcn_global_load_lds((as1_u32*)g, (as3_u32*)l, 16, 0, 0);
}

// ---------------------------------------------------------------------------
// small streaming kernels
// ---------------------------------------------------------------------------
__global__ __launch_bounds__(256) void cvt_x_kernel(
    const float* __restrict__ x, __bf16* __restrict__ xb)
{
    int i = (blockIdx.x * 256 + threadIdx.x) * 8;
    float4 f0 = *(const float4*)&x[i];
    float4 f1 = *(const float4*)&x[i + 4];
    bf16x8 h = { (__bf16)f0.x, (__bf16)f0.y, (__bf16)f0.z, (__bf16)f0.w,
                 (__bf16)f1.x, (__bf16)f1.y, (__bf16)f1.z, (__bf16)f1.w };
    *(bf16x8*)&xb[i] = h;
}

__global__ __launch_bounds__(256) void cvt_y_kernel(
    const float* __restrict__ Y32, __bf16* __restrict__ Y)
{
    int i = (blockIdx.x * 256 + threadIdx.x) * 8;
    float4 f0 = *(const float4*)&Y32[i];
    float4 f1 = *(const float4*)&Y32[i + 4];
    bf16x8 h = { (__bf16)f0.x, (__bf16)f0.y, (__bf16)f0.z, (__bf16)f0.w,
                 (__bf16)f1.x, (__bf16)f1.y, (__bf16)f1.z, (__bf16)f1.w };
    *(bf16x8*)&Y[i] = h;
}

__global__ __launch_bounds__(256) void cvt_rot_kernel(
    const float* __restrict__ Pi, const float* __restrict__ Pi2,
    __bf16* __restrict__ Pib)
{
    size_t i = ((size_t)blockIdx.x * 256 + threadIdx.x) * 8;
    const size_t half = (size_t)N_DIM * N_DIM;
    const float* src = (i < half) ? (Pi + i) : (Pi2 + (i - half));
    float4 f0 = *(const float4*)src;
    float4 f1 = *(const float4*)(src + 4);
    bf16x8 h = { (__bf16)f0.x, (__bf16)f0.y, (__bf16)f0.z, (__bf16)f0.w,
                 (__bf16)f1.x, (__bf16)f1.y, (__bf16)f1.z, (__bf16)f1.w };
    *(bf16x8*)&Pib[i] = h;
}

// Wcat (4096 x 8192): cols 0..4095 = pass1 weights, cols 4096.. = pass2.
__global__ __launch_bounds__(256) void dequant_kernel(
    const int*   __restrict__ idx1, const float* __restrict__ wn1,
    const float* __restrict__ cb1,
    const int*   __restrict__ idx2, const float* __restrict__ wn2,
    const float* __restrict__ cb2,
    __bf16* __restrict__ Wcat)
{
    __shared__ float2 lut[2][256];
    const int t = threadIdx.x;
    lut[0][t] = make_float2(cb1[t & 15] * INV_SQRT_G, cb1[(t >> 4) & 15] * INV_SQRT_G);
    lut[1][t] = make_float2(cb2[t & 15] * INV_SQRT_G, cb2[(t >> 4) & 15] * INV_SQRT_G);
    __syncthreads();

    const int f  = blockIdx.x * 256 + t;     // one 16-weight chunk per thread
    const int m  = f >> 9;                   // row
    const int jb = f & 511;                  // 16-col block within 8192
    const int pass = jb >> 8;
    const int jl = (jb & 255) * 16;          // pass-local col

    const int* ip = (pass ? idx2 : idx1) + (size_t)m * (N_DIM / 2) + (jl >> 1);
    const float ws = (pass ? wn2 : wn1)[m * 32 + (jl >> 7)];
    const float2* L = lut[pass];

    int4 v0 = *(const int4*)ip;
    int4 v1 = *(const int4*)(ip + 4);
    auto dq8 = [&](int4 v) -> bf16x8 {
        float2 p0 = L[v.x & 255], p1 = L[v.y & 255];
        float2 p2 = L[v.z & 255], p3 = L[v.w & 255];
        bf16x8 w = { (__bf16)(p0.x * ws), (__bf16)(p0.y * ws),
                     (__bf16)(p1.x * ws), (__bf16)(p1.y * ws),
                     (__bf16)(p2.x * ws), (__bf16)(p2.y * ws),
                     (__bf16)(p3.x * ws), (__bf16)(p3.y * ws) };
        return w;
    };
    __bf16* dst = &Wcat[(size_t)m * K2_DIM + jb * 16];
    *(bf16x8*)dst       = dq8(v0);
    *(bf16x8*)(dst + 8) = dq8(v1);
}

// ---------------------------------------------------------------------------
// Unified NT GEMM (m97 regime): C[m0+..,n0+..] += A-tile @ B-tile^T over a
// 1024-wide K chunk (blockIdx.z). A: (rows x lda) bf16, B: (cols x ldb) bf16.
// ---------------------------------------------------------------------------
__global__ __launch_bounds__(256, 3) void gemm_nt_kernel(
    const __bf16* __restrict__ A, const __bf16* __restrict__ B,
    float* __restrict__ C, int lda, int ldb, int ldc)
{
    __shared__ __bf16 sA[2][128 * 32];   // 8KB each
    __shared__ __bf16 sB[2][128 * 32];

    const int tid = threadIdx.x;
    const int n0  = blockIdx.x * 128;
    const int m0  = blockIdx.y * 128;
    const int k0  = blockIdx.z * 1024;

    const int wid = tid >> 6, lane = tid & 63;
    const int wr = (wid >> 1) * 64, wc = (wid & 1) * 64;
    const int lr = lane & 15, lg = lane >> 4;
    const int srow = lane >> 2, sunit = lane & 3;   // staging within 16-row chunk

    f32x4 acc[4][4] = {};

    auto issue = [&](int buf, int kk) {
        #pragma unroll
        for (int i = 0; i < 2; ++i) {
            const int c = wid * 2 + i;              // 16-row chunk 0..7
            gload16(&A[(size_t)(m0 + c * 16 + srow) * lda + kk + sunit * 8],
                    &sA[buf][c * 512]);
            gload16(&B[(size_t)(n0 + c * 16 + srow) * ldb + kk + sunit * 8],
                    &sB[buf][c * 512]);
        }
    };

    issue(0, k0);
    __syncthreads();

    int cur = 0;
    for (int k = 0; k < 32; ++k) {
        if (k + 1 < 32) issue(cur ^ 1, k0 + (k + 1) * 32);

        bf16x8 af[4], bf[4];
        #pragma unroll
        for (int m = 0; m < 4; ++m)
            af[m] = *(const bf16x8*)&sA[cur][(wr + m * 16 + lr) * 32 + lg * 8];
        #pragma unroll
        for (int n = 0; n < 4; ++n)
            bf[n] = *(const bf16x8*)&sB[cur][(wc + n * 16 + lr) * 32 + lg * 8];
        #pragma unroll
        for (int m = 0; m < 4; ++m)
            #pragma unroll
            for (int n = 0; n < 4; ++n)
                acc[m][n] = __builtin_amdgcn_mfma_f32_16x16x32_bf16(
                    af[m], bf[n], acc[m][n], 0, 0, 0);

        __syncthreads();
        cur ^= 1;
    }

    // C/D layout col=lane&15, row=(lane>>4)*4+e  [m89/m91]
    #pragma unroll
    for (int m = 0; m < 4; ++m)
        #pragma unroll
        for (int n = 0; n < 4; ++n)
            #pragma unroll
            for (int e = 0; e < 4; ++e)
                unsafeAtomicAdd(&C[(size_t)(m0 + wr + m * 16 + lg * 4 + e) * ldc +
                                   n0 + wc + n * 16 + lr], acc[m][n][e]);
}

// ---------------------------------------------------------------------------
// Fallback GEMMs (R4, proven): on-the-fly fp32-B / dequant-B, 28MB ws.
// ---------------------------------------------------------------------------
template<bool SPLITK>
__global__ __launch_bounds__(256, 3) void gemm1_fb_kernel(
    const __bf16* __restrict__ xb, const float* __restrict__ Pi,
    const float* __restrict__ Pi2, float* __restrict__ Y32,
    __bf16* __restrict__ Y)
{
    __shared__ __bf16 sA[2][128 * 32];
    __shared__ __bf16 sB[2][128 * 32];

    const int tid   = threadIdx.x;
    const int n0    = blockIdx.x * 128;
    const int t0    = blockIdx.y * 128;
    const int kbase = blockIdx.z * (SPLITK ? 1024 : N_DIM);
    const int NK    = (SPLITK ? 1024 : N_DIM) / 32;

    const float* Bsrc = (n0 < N_DIM) ? Pi : Pi2;
    const int nloc = n0 & (N_DIM - 1);

    const int wid = tid >> 6, lane = tid & 63;
    const int wr = (wid >> 1) * 64, wc = (wid & 1) * 64;
    const int lr = lane & 15, lg = lane >> 4;
    const int sw = lr & 3;

    const int arow = wid * 16 + (lane >> 2);
    const int acol = (lane & 3) * 8;
    const int br = tid >> 1, bh = tid & 1;

    f32x4 acc[4][4] = {};
    float4 rb[4];

    auto issueA = [&](int buf, int k0) {
        #pragma unroll
        for (int c = 0; c < 2; ++c)
            gload16(&xb[(size_t)(t0 + c * 64 + arow) * N_DIM + k0 + acol],
                    &sA[buf][(c * 64 + wid * 16) * 32]);
    };
    auto loadB = [&](int k0) {
        const float* bp = &Bsrc[(size_t)(nloc + br) * N_DIM + k0 + bh * 16];
        #pragma unroll
        for (int q = 0; q < 4; ++q) rb[q] = *(const float4*)(bp + q * 4);
    };
    auto writeB = [&](int buf) {
        #pragma unroll
        for (int h = 0; h < 2; ++h) {
            float4 f0 = rb[h * 2], f1 = rb[h * 2 + 1];
            bf16x8 v = { (__bf16)f0.x, (__bf16)f0.y, (__bf16)f0.z, (__bf16)f0.w,
                         (__bf16)f1.x, (__bf16)f1.y, (__bf16)f1.z, (__bf16)f1.w };
            int unit = (bh * 2 + h) ^ (br & 3);
            *(bf16x8*)&sB[buf][br * 32 + unit * 8] = v;
        }
    };

    loadB(kbase); issueA(0, kbase); writeB(0);
    __syncthreads();

    int cur = 0;
    for (int k = 0; k < NK; ++k) {
        const int kn = kbase + (k + 1) * 32;
        if (k + 1 < NK) { loadB(kn); issueA(cur ^ 1, kn); }

        bf16x8 af[4], bf[4];
        #pragma unroll
        for (int m = 0; m < 4; ++m)
            af[m] = *(const bf16x8*)&sA[cur][(wr + m * 16 + lr) * 32 + lg * 8];
        #pragma unroll
        for (int n = 0; n < 4; ++n)
            bf[n] = *(const bf16x8*)&sB[cur][(wc + n * 16 + lr) * 32 + (lg ^ sw) * 8];
        #pragma unroll
        for (int m = 0; m < 4; ++m)
            #pragma unroll
            for (int n = 0; n < 4; ++n)
                acc[m][n] = __builtin_amdgcn_mfma_f32_16x16x32_bf16(
                    af[m], bf[n], acc[m][n], 0, 0, 0);

        if (k + 1 < NK) writeB(cur ^ 1);
        __syncthreads();
        cur ^= 1;
    }

    #pragma unroll
    for (int m = 0; m < 4; ++m)
        #pragma unroll
        for (int n = 0; n < 4; ++n)
            #pragma unroll
            for (int e = 0; e < 4; ++e) {
                size_t off = (size_t)(t0 + wr + m * 16 + lg * 4 + e) * K2_DIM +
                             n0 + wc + n * 16 + lr;
                if (SPLITK) unsafeAtomicAdd(&Y32[off], acc[m][n][e]);
                else        Y[off] = (__bf16)acc[m][n][e];
            }
}

__global__ __launch_bounds__(256, 3) void gemm2_fb_kernel(
    const __bf16* __restrict__ Y,
    const int*   __restrict__ idx1, const float* __restrict__ wn1,
    const float* __restrict__ cb1,
    const int*   __restrict__ idx2, const float* __restrict__ wn2,
    const float* __restrict__ cb2,
    float* __restrict__ out)
{
    __shared__ __bf16 sA[2][128 * 32];
    __shared__ __bf16 sB[2][128 * 32];
    __shared__ float2 lut[256];

    const int tid  = threadIdx.x;
    const int m0   = blockIdx.x * 128;
    const int t0   = blockIdx.y * 128;
    const int pass = blockIdx.z >> 2;
    const int kof  = (blockIdx.z & 3) * 1024;

    const int*   idxp = pass ? idx2 : idx1;
    const float* wn   = pass ? wn2  : wn1;
    const float* cbg  = pass ? cb2  : cb1;

    lut[tid] = make_float2(cbg[tid & 15] * INV_SQRT_G,
                           cbg[(tid >> 4) & 15] * INV_SQRT_G);

    const int wid = tid >> 6, lane = tid & 63;
    const int wr = (wid >> 1) * 64, wc = (wid & 1) * 64;
    const int lr = lane & 15, lg = lane >> 4;
    const int sw = lr & 3;

    const int arow = wid * 16 + (lane >> 2);
    const int acol = (lane & 3) * 8;
    const int br = tid >> 1, bh = tid & 1;

    f32x4 acc[4][4] = {};
    int4  wi[2];
    float wscale;

    auto issueA = [&](int buf, int kl) {
        #pragma unroll
        for (int c = 0; c < 2; ++c)
            gload16(&Y[(size_t)(t0 + c * 64 + arow) * K2_DIM + pass * N_DIM + kl + acol],
                    &sA[buf][(c * 64 + wid * 16) * 32]);
    };
    auto loadB = [&](int kl) {
        const int* ip = &idxp[(size_t)(m0 + br) * (N_DIM / 2) + (kl >> 1) + bh * 8];
        wi[0] = *(const int4*)ip;
        wi[1] = *(const int4*)(ip + 4);
        wscale = wn[(size_t)(m0 + br) * 32 + (kl >> 7)];
    };
    auto writeB = [&](int buf) {
        #pragma unroll
        for (int h = 0; h < 2; ++h) {
            int4 v = wi[h];
            float2 p0 = lut[v.x & 255], p1 = lut[v.y & 255];
            float2 p2 = lut[v.z & 255], p3 = lut[v.w & 255];
            bf16x8 w = { (__bf16)(p0.x * wscale), (__bf16)(p0.y * wscale),
                         (__bf16)(p1.x * wscale), (__bf16)(p1.y * wscale),
                         (__bf16)(p2.x * wscale), (__bf16)(p2.y * wscale),
                         (__bf16)(p3.x * wscale), (__bf16)(p3.y * wscale) };
            int unit = (bh * 2 + h) ^ (br & 3);
            *(bf16x8*)&sB[buf][br * 32 + unit * 8] = w;
        }
    };

    loadB(kof); issueA(0, kof);
    __syncthreads();
    writeB(0);
    __syncthreads();

    int cur = 0;
    const int NK = 1024 / 32;
    for (int k = 0; k < NK; ++k) {
        const int kn = kof + (k + 1) * 32;
        if (k + 1 < NK) { loadB(kn); issueA(cur ^ 1, kn); }

        bf16x8 af[4], bf[4];
        #pragma unroll
        for (int m = 0; m < 4; ++m)
            af[m] = *(const bf16x8*)&sA[cur][(wr + m * 16 + lr) * 32 + lg * 8];
        #pragma unroll
        for (int n = 0; n < 4; ++n)
            bf[n] = *(const bf16x8*)&sB[cur][(wc + n * 16 + lr) * 32 + (lg ^ sw) * 8];
        #pragma unroll
        for (int m = 0; m < 4; ++m)
            #pragma unroll
            for (int n = 0; n < 4; ++n)
                acc[m][n] = __builtin_amdgcn_mfma_f32_16x16x32_bf16(
                    af[m], bf[n], acc[m][n], 0, 0, 0);

        if (k + 1 < NK) writeB(cur ^ 1);
        __syncthreads();
        cur ^= 1;
    }

    #pragma unroll
    for (int m = 0; m < 4; ++m)
        #pragma unroll
        for (int n = 0; n < 4; ++n)
            #pragma unroll
            for (int e = 0; e < 4; ++e)
                unsafeAtomicAdd(&out[(size_t)(t0 + wr + m * 16 + lg * 4 + e) * M_DIM +
                                     m0 + wc + n * 16 + lr], acc[m][n][e]);
}

// ---------------------------------------------------------------------------
extern "C" void kernel_launch(void* const* d_in, const int* in_sizes, int n_in,
                              void* d_out, int out_size, void* d_ws, size_t ws_size,
                              hipStream_t stream) {
    const float* x    = (const float*)d_in[0];
    const float* Pi   = (const float*)d_in[1];
    const int*   idx1 = (const int*)  d_in[2];
    const float* wn1  = (const float*)d_in[3];
    const float* cb1  = (const float*)d_in[4];
    const int*   idx2 = (const int*)  d_in[5];
    const float* wn2  = (const float*)d_in[6];
    const float* cb2  = (const float*)d_in[7];
    const float* Pi2  = (const float*)d_in[8];
    float* out = (float*)d_out;

    const size_t MB = 1024ull * 1024ull;
    // stable ws layout
    __bf16* xb   = (__bf16*)d_ws;                        // 4 MB
    float*  Y32  = (float*) ((char*)d_ws + 4  * MB);     // 16 MB
    __bf16* Ybf  = (__bf16*)((char*)d_ws + 20 * MB);     // 8 MB
    __bf16* Wcat = (__bf16*)((char*)d_ws + 28 * MB);     // 64 MB
    __bf16* Pib  = (__bf16*)((char*)d_ws + 92 * MB);     // 64 MB

    const bool fullT = ws_size >= 156 * MB;
    const bool midT  = ws_size >= 92 * MB;
    const bool lowT  = ws_size >= 28 * MB;

    hipMemsetAsync(out, 0, (size_t)T_DIM * M_DIM * sizeof(float), stream);
    cvt_x_kernel<<<dim3(T_DIM * N_DIM / (256 * 8)), dim3(256), 0, stream>>>(x, xb);

    if (midT)
        dequant_kernel<<<dim3(M_DIM * (K2_DIM / 16) / 256), dim3(256), 0, stream>>>(
            idx1, wn1, cb1, idx2, wn2, cb2, Wcat);

    // ---- pass 1: Y
    if (fullT) {
        cvt_rot_kernel<<<dim3(2 * N_DIM * N_DIM / (256 * 8)), dim3(256), 0, stream>>>(
            Pi, Pi2, Pib);
        hipMemsetAsync(Y32, 0, 16 * MB, stream);
        gemm_nt_kernel<<<dim3(K2_DIM / 128, T_DIM / 128, 4), dim3(256), 0, stream>>>(
            xb, Pib, Y32, N_DIM, N_DIM, K2_DIM);
        cvt_y_kernel<<<dim3(T_DIM * K2_DIM / (256 * 8)), dim3(256), 0, stream>>>(Y32, Ybf);
    } else if (lowT) {
        hipMemsetAsync(Y32, 0, 16 * MB, stream);
        gemm1_fb_kernel<true><<<dim3(K2_DIM / 128, T_DIM / 128, 4), dim3(256), 0, stream>>>(
            xb, Pi, Pi2, Y32, Ybf);
        cvt_y_kernel<<<dim3(T_DIM * K2_DIM / (256 * 8)), dim3(256), 0, stream>>>(Y32, Ybf);
    } else {
        __bf16* Ytiny = (__bf16*)((char*)d_ws + 4 * MB);
        gemm1_fb_kernel<false><<<dim3(K2_DIM / 128, T_DIM / 128, 1), dim3(256), 0, stream>>>(
            xb, Pi, Pi2, Y32, Ytiny);
        Ybf = Ytiny;
    }

    // ---- pass 2: out
    if (midT) {
        gemm_nt_kernel<<<dim3(M_DIM / 128, T_DIM / 128, 8), dim3(256), 0, stream>>>(
            Ybf, Wcat, out, K2_DIM, K2_DIM, M_DIM);
    } else {
        gemm2_fb_kernel<<<dim3(M_DIM / 128, T_DIM / 128, 8), dim3(256), 0, stream>>>(
            Ybf, idx1, wn1, cb1, idx2, wn2, cb2, out);
    }
}

// Round 6
// 334.128 us; speedup vs baseline: 1.2321x; 1.2321x over previous
//
#include <hip/hip_runtime.h>
#include <hip/hip_bf16.h>

// All-bf16 operand pipeline, atomic-free split-K with partial buffers:
//   xb   (512x4096  bf16, ws+0)    = cvt(x)
//   Pib  (8192x4096 bf16, ws+76MB) = cvt([Pi; Pi2])
//   P1   (4 x 512x8192 f32, ws+12MB) = xb @ Pib^T      (z=4 K-chunks of 1024)
//   Ybf  (512x8192  bf16, ws+4MB)  = reduce4(P1)
//   Wcat (4096x8192 bf16, ws+12MB) = dequant([W1|W2])  (overwrites P1 region)
//   P2   (8 x 512x4096 f32, ws+76MB) = Ybf @ Wcat^T    (z=8, overwrites Pib)
//   out  (512x4096  f32)           = reduce8(P2)
// GEMM: 128x128 tile, BK=32, 4 waves (2x2), wave-tile 64x64, acc 4x4,
// double-buffered LDS (32KB), both operands global_load_lds(16B), 4 blocks/CU.

typedef __bf16 bf16x8 __attribute__((ext_vector_type(8)));
typedef float  f32x4  __attribute__((ext_vector_type(4)));

#define T_DIM   512
#define N_DIM   4096
#define M_DIM   4096
#define K2_DIM  8192
#define INV_SQRT_G 0.08838834764831843f   // 1/sqrt(128)

typedef const __attribute__((address_space(1))) unsigned int as1_u32;
typedef __attribute__((address_space(3)))       unsigned int as3_u32;

__device__ __forceinline__ void gload16(const void* g, void* l) {
    // per-lane global src; LDS dst = wave-uniform base + lane*16 (m104)
    __builtin_amdgcn_global_load_lds((as1_u32*)g, (as3_u32*)l, 16, 0, 0);
}

// ---------------------------------------------------------------------------
// streaming kernels
// ---------------------------------------------------------------------------
__global__ __launch_bounds__(256) void cvt_x_kernel(
    const float* __restrict__ x, __bf16* __restrict__ xb)
{
    int i = (blockIdx.x * 256 + threadIdx.x) * 8;
    float4 f0 = *(const float4*)&x[i];
    float4 f1 = *(const float4*)&x[i + 4];
    bf16x8 h = { (__bf16)f0.x, (__bf16)f0.y, (__bf16)f0.z, (__bf16)f0.w,
                 (__bf16)f1.x, (__bf16)f1.y, (__bf16)f1.z, (__bf16)f1.w };
    *(bf16x8*)&xb[i] = h;
}

__global__ __launch_bounds__(256) void cvt_rot_kernel(
    const float* __restrict__ Pi, const float* __restrict__ Pi2,
    __bf16* __restrict__ Pib)
{
    size_t i = ((size_t)blockIdx.x * 256 + threadIdx.x) * 8;
    const size_t half = (size_t)N_DIM * N_DIM;
    const float* src = (i < half) ? (Pi + i) : (Pi2 + (i - half));
    float4 f0 = *(const float4*)src;
    float4 f1 = *(const float4*)(src + 4);
    bf16x8 h = { (__bf16)f0.x, (__bf16)f0.y, (__bf16)f0.z, (__bf16)f0.w,
                 (__bf16)f1.x, (__bf16)f1.y, (__bf16)f1.z, (__bf16)f1.w };
    *(bf16x8*)&Pib[i] = h;
}

// Wcat (4096 x 8192): cols 0..4095 = pass1 weights, cols 4096.. = pass2.
__global__ __launch_bounds__(256) void dequant_kernel(
    const int*   __restrict__ idx1, const float* __restrict__ wn1,
    const float* __restrict__ cb1,
    const int*   __restrict__ idx2, const float* __restrict__ wn2,
    const float* __restrict__ cb2,
    __bf16* __restrict__ Wcat)
{
    __shared__ float2 lut[2][256];
    const int t = threadIdx.x;
    lut[0][t] = make_float2(cb1[t & 15] * INV_SQRT_G, cb1[(t >> 4) & 15] * INV_SQRT_G);
    lut[1][t] = make_float2(cb2[t & 15] * INV_SQRT_G, cb2[(t >> 4) & 15] * INV_SQRT_G);
    __syncthreads();

    const int f  = blockIdx.x * 256 + t;     // one 16-weight chunk per thread
    const int m  = f >> 9;                   // row
    const int jb = f & 511;                  // 16-col block within 8192
    const int pass = jb >> 8;
    const int jl = (jb & 255) * 16;          // pass-local col

    const int* ip = (pass ? idx2 : idx1) + (size_t)m * (N_DIM / 2) + (jl >> 1);
    const float ws = (pass ? wn2 : wn1)[m * 32 + (jl >> 7)];
    const float2* L = lut[pass];

    int4 v0 = *(const int4*)ip;
    int4 v1 = *(const int4*)(ip + 4);
    auto dq8 = [&](int4 v) -> bf16x8 {
        float2 p0 = L[v.x & 255], p1 = L[v.y & 255];
        float2 p2 = L[v.z & 255], p3 = L[v.w & 255];
        bf16x8 w = { (__bf16)(p0.x * ws), (__bf16)(p0.y * ws),
                     (__bf16)(p1.x * ws), (__bf16)(p1.y * ws),
                     (__bf16)(p2.x * ws), (__bf16)(p2.y * ws),
                     (__bf16)(p3.x * ws), (__bf16)(p3.y * ws) };
        return w;
    };
    __bf16* dst = &Wcat[(size_t)m * K2_DIM + jb * 16];
    *(bf16x8*)dst       = dq8(v0);
    *(bf16x8*)(dst + 8) = dq8(v1);
}

// P1 partials (4 x 512x8192 f32) -> Ybf bf16
__global__ __launch_bounds__(256) void reduce_y_kernel(
    const float* __restrict__ P, __bf16* __restrict__ Ybf)
{
    const size_t stride = (size_t)T_DIM * K2_DIM;
    size_t i = ((size_t)blockIdx.x * 256 + threadIdx.x) * 8;
    float4 a0 = {0,0,0,0}, a1 = {0,0,0,0};
    #pragma unroll
    for (int z = 0; z < 4; ++z) {
        const float* p = P + z * stride + i;
        float4 f0 = *(const float4*)p;
        float4 f1 = *(const float4*)(p + 4);
        a0.x += f0.x; a0.y += f0.y; a0.z += f0.z; a0.w += f0.w;
        a1.x += f1.x; a1.y += f1.y; a1.z += f1.z; a1.w += f1.w;
    }
    bf16x8 h = { (__bf16)a0.x, (__bf16)a0.y, (__bf16)a0.z, (__bf16)a0.w,
                 (__bf16)a1.x, (__bf16)a1.y, (__bf16)a1.z, (__bf16)a1.w };
    *(bf16x8*)&Ybf[i] = h;
}

// P2 partials (8 x 512x4096 f32) -> out f32
__global__ __launch_bounds__(256) void reduce_out_kernel(
    const float* __restrict__ P, float* __restrict__ out)
{
    const size_t stride = (size_t)T_DIM * M_DIM;
    size_t i = ((size_t)blockIdx.x * 256 + threadIdx.x) * 8;
    float4 a0 = {0,0,0,0}, a1 = {0,0,0,0};
    #pragma unroll
    for (int z = 0; z < 8; ++z) {
        const float* p = P + z * stride + i;
        float4 f0 = *(const float4*)p;
        float4 f1 = *(const float4*)(p + 4);
        a0.x += f0.x; a0.y += f0.y; a0.z += f0.z; a0.w += f0.w;
        a1.x += f1.x; a1.y += f1.y; a1.z += f1.z; a1.w += f1.w;
    }
    *(float4*)&out[i]     = a0;
    *(float4*)&out[i + 4] = a1;
}

// ---------------------------------------------------------------------------
// Unified NT GEMM: Pz[m0.., n0..] = A-tile @ B-tile^T over K-chunk z*1024.
// A: (rows x lda) bf16, B: (cols x ldb) bf16, Pz: z-th partial (rows x ncols) f32.
// ---------------------------------------------------------------------------
__global__ __launch_bounds__(256, 4) void gemm_nt_kernel(
    const __bf16* __restrict__ A, const __bf16* __restrict__ B,
    float* __restrict__ P, int lda, int ldb, int ncols)
{
    __shared__ __bf16 sA[2][128 * 32];   // 8KB each
    __shared__ __bf16 sB[2][128 * 32];

    const int tid = threadIdx.x;
    const int n0  = blockIdx.x * 128;
    const int m0  = blockIdx.y * 128;
    const int k0  = blockIdx.z * 1024;
    float* Pz = P + (size_t)blockIdx.z * ((size_t)gridDim.y * 128) * ncols;

    const int wid = tid >> 6, lane = tid & 63;
    const int wr = (wid >> 1) * 64, wc = (wid & 1) * 64;
    const int lr = lane & 15, lg = lane >> 4;
    const int srow = lane >> 2, sunit = lane & 3;   // staging within 16-row chunk

    f32x4 acc[4][4] = {};

    auto issue = [&](int buf, int kk) {
        #pragma unroll
        for (int i = 0; i < 2; ++i) {
            const int c = wid * 2 + i;              // 16-row chunk 0..7
            gload16(&A[(size_t)(m0 + c * 16 + srow) * lda + kk + sunit * 8],
                    &sA[buf][c * 512]);
            gload16(&B[(size_t)(n0 + c * 16 + srow) * ldb + kk + sunit * 8],
                    &sB[buf][c * 512]);
        }
    };

    issue(0, k0);
    __syncthreads();

    int cur = 0;
    for (int k = 0; k < 32; ++k) {
        if (k + 1 < 32) issue(cur ^ 1, k0 + (k + 1) * 32);

        bf16x8 af[4], bf[4];
        #pragma unroll
        for (int m = 0; m < 4; ++m)
            af[m] = *(const bf16x8*)&sA[cur][(wr + m * 16 + lr) * 32 + lg * 8];
        #pragma unroll
        for (int n = 0; n < 4; ++n)
            bf[n] = *(const bf16x8*)&sB[cur][(wc + n * 16 + lr) * 32 + lg * 8];
        #pragma unroll
        for (int m = 0; m < 4; ++m)
            #pragma unroll
            for (int n = 0; n < 4; ++n)
                acc[m][n] = __builtin_amdgcn_mfma_f32_16x16x32_bf16(
                    af[m], bf[n], acc[m][n], 0, 0, 0);

        __syncthreads();
        cur ^= 1;
    }

    // C/D layout col=lane&15, row=(lane>>4)*4+e  [m89/m91]; plain stores
    #pragma unroll
    for (int m = 0; m < 4; ++m)
        #pragma unroll
        for (int n = 0; n < 4; ++n)
            #pragma unroll
            for (int e = 0; e < 4; ++e)
                Pz[(size_t)(m0 + wr + m * 16 + lg * 4 + e) * ncols +
                   n0 + wc + n * 16 + lr] = acc[m][n][e];
}

// ---------------------------------------------------------------------------
extern "C" void kernel_launch(void* const* d_in, const int* in_sizes, int n_in,
                              void* d_out, int out_size, void* d_ws, size_t ws_size,
                              hipStream_t stream) {
    const float* x    = (const float*)d_in[0];
    const float* Pi   = (const float*)d_in[1];
    const int*   idx1 = (const int*)  d_in[2];
    const float* wn1  = (const float*)d_in[3];
    const float* cb1  = (const float*)d_in[4];
    const int*   idx2 = (const int*)  d_in[5];
    const float* wn2  = (const float*)d_in[6];
    const float* cb2  = (const float*)d_in[7];
    const float* Pi2  = (const float*)d_in[8];
    float* out = (float*)d_out;

    const size_t MB = 1024ull * 1024ull;
    // ws layout (140MB total; R5 proved ws_size >= 156MB):
    //   [0,4)    xb          512x4096 bf16
    //   [4,12)   Ybf         512x8192 bf16
    //   [12,76)  P1 partials 4 x 512x8192 f32   -> later Wcat 4096x8192 bf16
    //   [76,140) Pib         8192x4096 bf16     -> later P2 8 x 512x4096 f32
    __bf16* xb   = (__bf16*)d_ws;
    __bf16* Ybf  = (__bf16*)((char*)d_ws + 4  * MB);
    float*  P1   = (float*) ((char*)d_ws + 12 * MB);
    __bf16* Wcat = (__bf16*)((char*)d_ws + 12 * MB);
    __bf16* Pib  = (__bf16*)((char*)d_ws + 76 * MB);
    float*  P2   = (float*) ((char*)d_ws + 76 * MB);

    cvt_x_kernel<<<dim3(T_DIM * N_DIM / (256 * 8)), dim3(256), 0, stream>>>(x, xb);
    cvt_rot_kernel<<<dim3(2 * N_DIM * N_DIM / (256 * 8)), dim3(256), 0, stream>>>(
        Pi, Pi2, Pib);

    // pass 1: Y = xb @ Pib^T  (4 K-chunks -> P1, reduce -> Ybf)
    gemm_nt_kernel<<<dim3(K2_DIM / 128, T_DIM / 128, 4), dim3(256), 0, stream>>>(
        xb, Pib, P1, N_DIM, N_DIM, K2_DIM);
    reduce_y_kernel<<<dim3(T_DIM * K2_DIM / (256 * 8)), dim3(256), 0, stream>>>(P1, Ybf);

    // dequant after reduce_y (Wcat overwrites P1 region)
    dequant_kernel<<<dim3(M_DIM * (K2_DIM / 16) / 256), dim3(256), 0, stream>>>(
        idx1, wn1, cb1, idx2, wn2, cb2, Wcat);

    // pass 2: out = Ybf @ Wcat^T  (8 K-chunks -> P2, reduce -> out)
    gemm_nt_kernel<<<dim3(M_DIM / 128, T_DIM / 128, 8), dim3(256), 0, stream>>>(
        Ybf, Wcat, P2, K2_DIM, K2_DIM, M_DIM);
    reduce_out_kernel<<<dim3(T_DIM * M_DIM / (256 * 8)), dim3(256), 0, stream>>>(P2, out);
}

// Round 8
// 327.528 us; speedup vs baseline: 1.2569x; 1.0201x over previous
//
#include <hip/hip_runtime.h>
#include <hip/hip_bf16.h>

// All-bf16 operand pipeline, atomic-free split-K with partial buffers:
//   prep:  xb (512x4096 bf16) = cvt(x); Pib (8192x4096 bf16) = cvt([Pi;Pi2])
//   gemm1: P1 (4 x 512x8192 f32) = xb @ Pib^T   (z=4 K-chunks of 1024)
//   mid:   Ybf (512x8192 bf16) = reduce4(P1);  Wcat (4096x8192 bf16) = dequant
//   gemm2: P2 (8 x 512x4096 f32) = Ybf @ Wcat^T (z=8)
//   reduce_out: out = reduce8(P2)
// GEMM: 128x128 tile, BK=32, 4 waves (2x2), wave-tile 64x64, acc 4x4,
// double-buffered LDS (32KB), both operands global_load_lds(16B).
// Streaming kernels: one contiguous float4/int4 per lane (m13 6.3TB/s pattern).

typedef __bf16 bf16x8 __attribute__((ext_vector_type(8)));
typedef __bf16 bf16x4 __attribute__((ext_vector_type(4)));
typedef float  f32x4  __attribute__((ext_vector_type(4)));

#define T_DIM   512
#define N_DIM   4096
#define M_DIM   4096
#define K2_DIM  8192
#define INV_SQRT_G 0.08838834764831843f   // 1/sqrt(128)

typedef const __attribute__((address_space(1))) unsigned int as1_u32;
typedef __attribute__((address_space(3)))       unsigned int as3_u32;

__device__ __forceinline__ void gload16(const void* g, void* l) {
    // per-lane global src; LDS dst = wave-uniform base + lane*16 (m104)
    __builtin_amdgcn_global_load_lds((as1_u32*)g, (as3_u32*)l, 16, 0, 0);
}

// ---------------------------------------------------------------------------
// prep: cvt x -> xb  and [Pi;Pi2] -> Pib, one float4 per lane, 2 per thread.
// Linear float4 space: [0, X4) = x, [X4, X4+R4) = Pi, [X4+R4, X4+2R4) = Pi2.
// ---------------------------------------------------------------------------
__global__ __launch_bounds__(256) void prep_kernel(
    const float* __restrict__ x, const float* __restrict__ Pi,
    const float* __restrict__ Pi2,
    __bf16* __restrict__ xb, __bf16* __restrict__ Pib)
{
    const size_t X4 = (size_t)T_DIM * N_DIM / 4;    // 524288
    const size_t R4 = (size_t)N_DIM * N_DIM / 4;    // 4194304
    #pragma unroll
    for (int k = 0; k < 2; ++k) {
        size_t g = (size_t)blockIdx.x * 512 + k * 256 + threadIdx.x;
        const float* src;
        __bf16* dst;
        if (g < X4)           { src = x   + g * 4;             dst = xb  + g * 4; }
        else if (g < X4 + R4) { src = Pi  + (g - X4) * 4;      dst = Pib + (g - X4) * 4; }
        else                  { src = Pi2 + (g - X4 - R4) * 4; dst = Pib + (g - X4) * 4; }
        float4 f = *(const float4*)src;
        bf16x4 h = { (__bf16)f.x, (__bf16)f.y, (__bf16)f.z, (__bf16)f.w };
        *(bf16x4*)dst = h;
    }
}

// ---------------------------------------------------------------------------
// mid: blocks [0,4096) reduce P1 -> Ybf; blocks [4096,20480) dequant -> Wcat.
// ---------------------------------------------------------------------------
__global__ __launch_bounds__(256) void mid_kernel(
    const float* __restrict__ P1, __bf16* __restrict__ Ybf,
    const int*   __restrict__ idx1, const float* __restrict__ wn1,
    const float* __restrict__ cb1,
    const int*   __restrict__ idx2, const float* __restrict__ wn2,
    const float* __restrict__ cb2,
    __bf16* __restrict__ Wcat)
{
    if (blockIdx.x < 4096) {
        // reduce_y: one float4 per lane from each of 4 partials
        size_t i = ((size_t)blockIdx.x * 256 + threadIdx.x) * 4;
        const size_t stride = (size_t)T_DIM * K2_DIM;
        float4 a = {0.f, 0.f, 0.f, 0.f};
        #pragma unroll
        for (int z = 0; z < 4; ++z) {
            float4 f = *(const float4*)(P1 + z * stride + i);
            a.x += f.x; a.y += f.y; a.z += f.z; a.w += f.w;
        }
        bf16x4 h = { (__bf16)a.x, (__bf16)a.y, (__bf16)a.z, (__bf16)a.w };
        *(bf16x4*)&Ybf[i] = h;
    } else {
        __shared__ float2 lut[2][256];
        const int t = threadIdx.x;
        lut[0][t] = make_float2(cb1[t & 15] * INV_SQRT_G, cb1[(t >> 4) & 15] * INV_SQRT_G);
        lut[1][t] = make_float2(cb2[t & 15] * INV_SQRT_G, cb2[(t >> 4) & 15] * INV_SQRT_G);
        __syncthreads();

        // one int4 (= 8 int32-bytes = 8 weights) per lane
        const int f    = (blockIdx.x - 4096) * 256 + t;   // int4 id, [0, 4M)
        const int pass = f >> 21;                          // 2M int4 per pass
        const int i4   = f & ((1 << 21) - 1);
        const int m    = i4 >> 9;                          // 512 int4 per row
        const int c    = i4 & 511;

        const int* ip = (pass ? idx2 : idx1) + ((size_t)m << 11) + c * 4;
        const float ws = (pass ? wn2 : wn1)[m * 32 + (c >> 4)];
        const float2* L = lut[pass];

        int4 v = *(const int4*)ip;
        float2 p0 = L[v.x & 255], p1 = L[v.y & 255];
        float2 p2 = L[v.z & 255], p3 = L[v.w & 255];
        bf16x8 w = { (__bf16)(p0.x * ws), (__bf16)(p0.y * ws),
                     (__bf16)(p1.x * ws), (__bf16)(p1.y * ws),
                     (__bf16)(p2.x * ws), (__bf16)(p2.y * ws),
                     (__bf16)(p3.x * ws), (__bf16)(p3.y * ws) };
        *(bf16x8*)&Wcat[((size_t)m << 13) + (pass << 12) + c * 8] = w;
    }
}

// ---------------------------------------------------------------------------
// reduce_out: one float4 per lane from each of 8 partials -> out f32
// ---------------------------------------------------------------------------
__global__ __launch_bounds__(256) void reduce_out_kernel(
    const float* __restrict__ P, float* __restrict__ out)
{
    const size_t stride = (size_t)T_DIM * M_DIM;
    size_t i = ((size_t)blockIdx.x * 256 + threadIdx.x) * 4;
    float4 a = {0.f, 0.f, 0.f, 0.f};
    #pragma unroll
    for (int z = 0; z < 8; ++z) {
        float4 f = *(const float4*)(P + z * stride + i);
        a.x += f.x; a.y += f.y; a.z += f.z; a.w += f.w;
    }
    *(float4*)&out[i] = a;
}

// ---------------------------------------------------------------------------
// Unified NT GEMM: Pz[m0.., n0..] = A-tile @ B-tile^T over K-chunk z*1024.
// A: (rows x lda) bf16, B: (cols x ldb) bf16, Pz: z-th partial (rows x ncols) f32.
// ---------------------------------------------------------------------------
__global__ __launch_bounds__(256, 4) void gemm_nt_kernel(
    const __bf16* __restrict__ A, const __bf16* __restrict__ B,
    float* __restrict__ P, int lda, int ldb, int ncols)
{
    __shared__ __bf16 sA[2][128 * 32];   // 8KB each
    __shared__ __bf16 sB[2][128 * 32];

    const int tid = threadIdx.x;
    const int n0  = blockIdx.x * 128;
    const int m0  = blockIdx.y * 128;
    const int k0  = blockIdx.z * 1024;
    float* Pz = P + (size_t)blockIdx.z * ((size_t)gridDim.y * 128) * ncols;

    const int wid = tid >> 6, lane = tid & 63;
    const int wr = (wid >> 1) * 64, wc = (wid & 1) * 64;
    const int lr = lane & 15, lg = lane >> 4;
    const int srow = lane >> 2, sunit = lane & 3;   // staging within 16-row chunk

    f32x4 acc[4][4] = {};

    auto issue = [&](int buf, int kk) {
        #pragma unroll
        for (int i = 0; i < 2; ++i) {
            const int c = wid * 2 + i;              // 16-row chunk 0..7
            gload16(&A[(size_t)(m0 + c * 16 + srow) * lda + kk + sunit * 8],
                    &sA[buf][c * 512]);
            gload16(&B[(size_t)(n0 + c * 16 + srow) * ldb + kk + sunit * 8],
                    &sB[buf][c * 512]);
        }
    };

    issue(0, k0);
    __syncthreads();

    int cur = 0;
    for (int k = 0; k < 32; ++k) {
        if (k + 1 < 32) issue(cur ^ 1, k0 + (k + 1) * 32);

        bf16x8 af[4], bf[4];
        #pragma unroll
        for (int m = 0; m < 4; ++m)
            af[m] = *(const bf16x8*)&sA[cur][(wr + m * 16 + lr) * 32 + lg * 8];
        #pragma unroll
        for (int n = 0; n < 4; ++n)
            bf[n] = *(const bf16x8*)&sB[cur][(wc + n * 16 + lr) * 32 + lg * 8];
        #pragma unroll
        for (int m = 0; m < 4; ++m)
            #pragma unroll
            for (int n = 0; n < 4; ++n)
                acc[m][n] = __builtin_amdgcn_mfma_f32_16x16x32_bf16(
                    af[m], bf[n], acc[m][n], 0, 0, 0);

        __syncthreads();
        cur ^= 1;
    }

    // C/D layout col=lane&15, row=(lane>>4)*4+e  [m89/m91]; plain stores
    #pragma unroll
    for (int m = 0; m < 4; ++m)
        #pragma unroll
        for (int n = 0; n < 4; ++n)
            #pragma unroll
            for (int e = 0; e < 4; ++e)
                Pz[(size_t)(m0 + wr + m * 16 + lg * 4 + e) * ncols +
                   n0 + wc + n * 16 + lr] = acc[m][n][e];
}

// ---------------------------------------------------------------------------
extern "C" void kernel_launch(void* const* d_in, const int* in_sizes, int n_in,
                              void* d_out, int out_size, void* d_ws, size_t ws_size,
                              hipStream_t stream) {
    const float* x    = (const float*)d_in[0];
    const float* Pi   = (const float*)d_in[1];
    const int*   idx1 = (const int*)  d_in[2];
    const float* wn1  = (const float*)d_in[3];
    const float* cb1  = (const float*)d_in[4];
    const int*   idx2 = (const int*)  d_in[5];
    const float* wn2  = (const float*)d_in[6];
    const float* cb2  = (const float*)d_in[7];
    const float* Pi2  = (const float*)d_in[8];
    float* out = (float*)d_out;

    const size_t MB = 1024ull * 1024ull;
    // ws layout (140MB; proven ws_size >= 156MB):
    //   [0,4)    xb          512x4096 bf16
    //   [4,12)   Ybf         512x8192 bf16
    //   [12,76)  P1 partials 4 x 512x8192 f32   -> later Wcat 4096x8192 bf16
    //   [76,140) Pib         8192x4096 bf16     -> later P2 8 x 512x4096 f32
    __bf16* xb   = (__bf16*)d_ws;
    __bf16* Ybf  = (__bf16*)((char*)d_ws + 4  * MB);
    float*  P1   = (float*) ((char*)d_ws + 12 * MB);
    __bf16* Wcat = (__bf16*)((char*)d_ws + 12 * MB);
    __bf16* Pib  = (__bf16*)((char*)d_ws + 76 * MB);
    float*  P2   = (float*) ((char*)d_ws + 76 * MB);

    // prep: (X4 + 2*R4) float4s, 2 per thread -> 17408 blocks
    prep_kernel<<<dim3(17408), dim3(256), 0, stream>>>(x, Pi, Pi2, xb, Pib);

    // pass 1: Y = xb @ Pib^T  (4 K-chunks -> P1)
    gemm_nt_kernel<<<dim3(K2_DIM / 128, T_DIM / 128, 4), dim3(256), 0, stream>>>(
        xb, Pib, P1, N_DIM, N_DIM, K2_DIM);

    // mid: reduce4(P1) -> Ybf (4096 blocks) + dequant -> Wcat (16384 blocks)
    mid_kernel<<<dim3(20480), dim3(256), 0, stream>>>(
        P1, Ybf, idx1, wn1, cb1, idx2, wn2, cb2, Wcat);

    // pass 2: out_partials = Ybf @ Wcat^T  (8 K-chunks -> P2)
    gemm_nt_kernel<<<dim3(M_DIM / 128, T_DIM / 128, 8), dim3(256), 0, stream>>>(
        Ybf, Wcat, P2, K2_DIM, K2_DIM, M_DIM);

    reduce_out_kernel<<<dim3(T_DIM * M_DIM / (256 * 4)), dim3(256), 0, stream>>>(P2, out);
}